// Round 5
// baseline (229.725 us; speedup 1.0000x reference)
//
#include <hip/hip_runtime.h>

#define BS     8192
#define DIM    768
#define NPART  32               // BS / BN column partitions
#define BM     256
#define BN     256
#define BK     32
#define NKT    (DIM / BK)       // 24 k-tiles
#define L1B    128              // loss stage-1 blocks
#define L1R    (BS / L1B)       // rows per stage-1 block (64)

typedef __bf16 bfrag_t __attribute__((ext_vector_type(8)));
typedef float  facc_t  __attribute__((ext_vector_type(4)));
typedef float  f4raw   __attribute__((ext_vector_type(4)));

typedef const __attribute__((address_space(1))) void gv_t;
typedef __attribute__((address_space(3))) void lv_t;

__device__ __forceinline__ void gll16(const void* g, void* l) {
  // async global->LDS DMA, 16B/lane; LDS dest = wave-uniform base + lane*16
  __builtin_amdgcn_global_load_lds((gv_t*)g, (lv_t*)l, 16, 0, 0);
}

__device__ __forceinline__ unsigned short f2bf(float f) {
  union { float f; unsigned u; } v; v.f = f;
  unsigned u = v.u;
  return (unsigned short)((u + 0x7FFFu + ((u >> 16) & 1u)) >> 16);  // RNE
}

// ---------------- fused: fp32 copy-out (both), bf16 convert (both), diag ----------------
__global__ void prep_kernel(const float* __restrict__ nl, const float* __restrict__ cd,
                            float* __restrict__ cd_copy, float* __restrict__ nl_copy,
                            unsigned short* __restrict__ nlb, unsigned short* __restrict__ cdb,
                            float* __restrict__ dg) {
  const int lane = threadIdx.x & 63;
  const int wave = threadIdx.x >> 6;
  const int row  = blockIdx.x * 4 + wave;
  const size_t rbase = (size_t)row * DIM;
  const float4* ar = reinterpret_cast<const float4*>(nl + rbase);
  const float4* br = reinterpret_cast<const float4*>(cd + rbase);
  float4* wa = reinterpret_cast<float4*>(nl_copy + rbase);
  float4* wb = reinterpret_cast<float4*>(cd_copy + rbase);
  ushort4* ba = reinterpret_cast<ushort4*>(nlb + rbase);
  ushort4* bb = reinterpret_cast<ushort4*>(cdb + rbase);

  float s = 0.f;
#pragma unroll
  for (int i = 0; i < 3; ++i) {                 // 192 float4 per row, 3 per lane
    int idx = lane + 64 * i;
    float4 x = ar[idx];
    float4 y = br[idx];
    wa[idx] = x;
    wb[idx] = y;
    ushort4 xb, yb;
    xb.x = f2bf(x.x); xb.y = f2bf(x.y); xb.z = f2bf(x.z); xb.w = f2bf(x.w);
    yb.x = f2bf(y.x); yb.y = f2bf(y.y); yb.z = f2bf(y.z); yb.w = f2bf(y.w);
    ba[idx] = xb;
    bb[idx] = yb;
    s += x.x * y.x + x.y * y.y + x.z * y.z + x.w * y.w;
  }
#pragma unroll
  for (int off = 32; off; off >>= 1) s += __shfl_xor(s, off, 64);
  if (lane == 0) dg[row] = s;
}

// ---------------- 256x256 software-pipelined GEMM (bf16 MFMA) + lse partials ----------------
// K-tile = 32, 24 tiles, triple-buffered LDS (96 KB), 2 phases per K-tile.
// READ-AHEAD pipeline: each phase's ds_reads feed the NEXT phase's MFMA; the phase-top
// wait is a COUNTED s_waitcnt lgkmcnt(N) so the current phase's reads drain UNDER the
// current MFMA.
// PUBLICATION RULE (the R4 bug): counted vmcnt must sit IMMEDIATELY BEFORE an s_barrier,
// and consumers read only AFTER that barrier — vmcnt is per-wave, so a wave's own wait
// says nothing about other waves' DMA slices until a barrier follows everyone's wait.
//   phase A(k): [read afH(k) x4 | STG A(k+2)]  bar  lgkm(4)  MFMA(afL x bf(k), mt0-3)
//               setprio0  vmcnt(2)  bar          <- publishes tile k+1 to all waves
//   phase B(k): [read bf(k+1) x4 + afL(k+1) x4 | STG B(k+2)]
//                                              bar  lgkm(8)  MFMA(afH x bf(k), mt4-7)
// End-of-phase-A outstanding loads: {A(k+1), B(k+1), A(k+2)} = 6 -> vmcnt(2) drains
// tile k+1 exactly (needed loads are always the OLDEST). k=22 uses vmcnt(0).
// LDS layout (64B rows would be 8-way bank-degenerate): rows packed in PAIRS of 128B,
// physical 16B slot = ((rowbit0<<2)|c8) ^ (rowpair&7). gll16 writes linearly; the
// GLOBAL source address is inverse-swizzled per-thread (both-sides-or-neither rule).
__global__ __launch_bounds__(512, 2) void gemm_lse_kernel(
    const unsigned short* __restrict__ Abf,
    const unsigned short* __restrict__ Bbf,
    float* __restrict__ pm, float* __restrict__ pl) {
  __shared__ __align__(16) unsigned short LDSU[49152];   // 96 KB: A bufs 0-2, B bufs 0-2

  const int tid  = threadIdx.x;
  const int lane = tid & 63;
  const int wave = tid >> 6;
  const int wm   = wave >> 2;      // 0..1  M half
  const int wn   = wave & 3;       // 0..3  N quarter
  const int l15  = lane & 15;
  const int l4   = lane >> 4;

  // XCD-chunk swizzle: 1024 blocks = 8 XCDs x 128; each XCD gets 4 rb-rows x all cb
  unsigned lin = blockIdx.y * 32 + blockIdx.x;
  unsigned swz = (lin & 7) * 128 + (lin >> 3);
  const int cb = swz & 31;
  const int rb = swz >> 5;

  // ---- staging source (inverse-swizzled): LDS unit u <- global(row=2a+b, c8), where
  //      a=u>>3, s=u&7, l=s^(a&7), b=(l>>2)&1, c8=l&3
  const int a0_ = tid >> 3, s0_ = tid & 7, l0_ = s0_ ^ (a0_ & 7);
  const int grow = 2 * a0_ + ((l0_ >> 2) & 1);
  const int gc8  = l0_ & 3;
  const unsigned short* srcA0 = Abf + (size_t)(rb * BM + grow) * DIM + gc8 * 8;
  const unsigned short* srcB0 = Bbf + (size_t)(cb * BN + grow) * DIM + gc8 * 8;
  char* dstA0 = (char*)LDSU + tid * 16;
  char* dstB0 = (char*)LDSU + 49152 + tid * 16;

#define STGA(k) do{ gll16(srcA0 + (size_t)(k) * 32,                    dstA0 + ((k) % 3) * 16384); \
                    gll16(srcA0 + (size_t)128 * DIM + (size_t)(k) * 32, dstA0 + ((k) % 3) * 16384 + 8192);}while(0)
#define STGB(k) do{ gll16(srcB0 + (size_t)(k) * 32,                    dstB0 + ((k) % 3) * 16384); \
                    gll16(srcB0 + (size_t)128 * DIM + (size_t)(k) * 32, dstB0 + ((k) % 3) * 16384 + 8192);}while(0)

  // ---- fragment-read addresses: row = (wm*128|wn*64) + t*16 + l15, k-slot c8 = l4
  //      a = row>>1 (a&7 = (l15>>1)&7, invariant in t), phys = ((row&1)<<2|l4) ^ (a&7)
  const unsigned lds32 = (unsigned)(uintptr_t)(void*)&LDSU[0];
  const unsigned physA = ((unsigned)(((l15 & 1) << 2) | l4)) ^ (unsigned)((l15 >> 1) & 7);
  const unsigned abase = lds32 + (unsigned)(wm * 64 + (l15 >> 1)) * 128 + physA * 16;
  const unsigned bbase = lds32 + 49152u + (unsigned)(wn * 32 + (l15 >> 1)) * 128 + physA * 16;

  f4raw afL[4], afH[4], bfE[4], bfO[4];
  facc_t acc[8][4];
#pragma unroll
  for (int mt = 0; mt < 8; ++mt)
#pragma unroll
    for (int nt = 0; nt < 4; ++nt) acc[mt][nt] = (facc_t){0.f, 0.f, 0.f, 0.f};

#define DSR(dst, addr, off) \
  asm volatile("ds_read_b128 %0, %1 offset:%2" : "=v"(dst) : "v"(addr), "n"(off))
#define RD4(ARR, base, off) do{ \
    DSR(ARR[0], base, (off) + 0 * 1024); DSR(ARR[1], base, (off) + 1 * 1024); \
    DSR(ARR[2], base, (off) + 2 * 1024); DSR(ARR[3], base, (off) + 3 * 1024); }while(0)

#define MFMA_PH(AF, BF, half) do{ \
    _Pragma("unroll") \
    for (int m_ = 0; m_ < 4; ++m_) \
      _Pragma("unroll") \
      for (int n_ = 0; n_ < 4; ++n_) \
        acc[(half) * 4 + m_][n_] = __builtin_amdgcn_mfma_f32_16x16x32_bf16( \
            __builtin_bit_cast(bfrag_t, AF[m_]), __builtin_bit_cast(bfrag_t, BF[n_]), \
            acc[(half) * 4 + m_][n_], 0, 0, 0); \
  }while(0)

#define TOPN(n) do{ __builtin_amdgcn_sched_barrier(0); __builtin_amdgcn_s_barrier(); \
    asm volatile("s_waitcnt lgkmcnt(" #n ")"); __builtin_amdgcn_sched_barrier(0); \
    __builtin_amdgcn_s_setprio(1);}while(0)
#define BOT() do{ __builtin_amdgcn_s_setprio(0); __builtin_amdgcn_sched_barrier(0); \
    __builtin_amdgcn_s_barrier();}while(0)
#define BOTVM(n) do{ __builtin_amdgcn_s_setprio(0); __builtin_amdgcn_sched_barrier(0); \
    asm volatile("s_waitcnt vmcnt(" #n ")"); __builtin_amdgcn_sched_barrier(0); \
    __builtin_amdgcn_s_barrier();}while(0)

#define KT(k, BFC, BFN, VMN) do{ \
    /* phase A(k) */ \
    RD4(afH, abase, ((k) % 3) * 16384 + 4096); \
    if ((k) <= 21) STGA((k) + 2); \
    TOPN(4); \
    MFMA_PH(afL, BFC, 0); \
    BOTVM(VMN);                                   /* vmcnt THEN barrier: publish tile k+1 */ \
    /* phase B(k) */ \
    RD4(BFN, bbase, (((k) + 1) % 3) * 16384); \
    RD4(afL, abase, (((k) + 1) % 3) * 16384); \
    if ((k) <= 21) STGB((k) + 2); \
    TOPN(8); \
    MFMA_PH(afH, BFC, 1); \
    BOT(); \
  }while(0)

  // prologue: tiles 0,1 staged; tile0 published (vmcnt(4) then barrier); pre-read bf(0)+afL(0)
  STGA(0); STGB(0); STGA(1); STGB(1);
  __builtin_amdgcn_sched_barrier(0);
  asm volatile("s_waitcnt vmcnt(4)");
  __builtin_amdgcn_sched_barrier(0);
  __builtin_amdgcn_s_barrier();
  RD4(bfE, bbase, 0);
  RD4(afL, abase, 0);

  KT(0,  bfE, bfO, 2); KT(1,  bfO, bfE, 2); KT(2,  bfE, bfO, 2); KT(3,  bfO, bfE, 2);
  KT(4,  bfE, bfO, 2); KT(5,  bfO, bfE, 2); KT(6,  bfE, bfO, 2); KT(7,  bfO, bfE, 2);
  KT(8,  bfE, bfO, 2); KT(9,  bfO, bfE, 2); KT(10, bfE, bfO, 2); KT(11, bfO, bfE, 2);
  KT(12, bfE, bfO, 2); KT(13, bfO, bfE, 2); KT(14, bfE, bfO, 2); KT(15, bfO, bfE, 2);
  KT(16, bfE, bfO, 2); KT(17, bfO, bfE, 2); KT(18, bfE, bfO, 2); KT(19, bfO, bfE, 2);
  KT(20, bfE, bfO, 2); KT(21, bfO, bfE, 2); KT(22, bfE, bfO, 0);

  // k = 23 (buf 2, odd -> current bf = bfO): no further reads/stages
  RD4(afH, abase, 2 * 16384 + 4096);
  TOPN(4);
  MFMA_PH(afL, bfO, 0);
  BOT();
  TOPN(0);
  MFMA_PH(afH, bfO, 1);
  BOT();

  // ---------------- epilogue: row-wise (max, sumexp) over this block's 256 cols ----------------
  float* cm = reinterpret_cast<float*>(LDSU);            // [4][BM] wn-major scratch (4 KB)
  float* cl = reinterpret_cast<float*>(LDSU + 2048);     // byte 4096+, 4 KB
  __syncthreads();
#pragma unroll
  for (int mt = 0; mt < 8; ++mt)
#pragma unroll
    for (int r = 0; r < 4; ++r) {
      float v0 = acc[mt][0][r], v1 = acc[mt][1][r], v2 = acc[mt][2][r], v3 = acc[mt][3][r];
      float m = fmaxf(fmaxf(v0, v1), fmaxf(v2, v3));
      float l = __expf(v0 - m) + __expf(v1 - m) + __expf(v2 - m) + __expf(v3 - m);
#pragma unroll
      for (int mask = 1; mask < 16; mask <<= 1) {   // combine 16 col-subsets (same row)
        float om = __shfl_xor(m, mask, 64);
        float ol = __shfl_xor(l, mask, 64);
        float mn = fmaxf(m, om);
        l = l * __expf(m - mn) + ol * __expf(om - mn);
        m = mn;
      }
      if (l15 == 0) {
        int rl = wm * 128 + mt * 16 + l4 * 4 + r;
        cm[wn * BM + rl] = m;
        cl[wn * BM + rl] = l;
      }
    }
  __syncthreads();
  if (tid < BM) {
    float m0 = cm[tid],          l0 = cl[tid];
    float m1 = cm[BM + tid],     l1 = cl[BM + tid];
    float m2 = cm[2 * BM + tid], l2 = cl[2 * BM + tid];
    float m3 = cm[3 * BM + tid], l3 = cl[3 * BM + tid];
    float mn = fmaxf(fmaxf(m0, m1), fmaxf(m2, m3));
    float ll = l0 * __expf(m0 - mn) + l1 * __expf(m1 - mn) +
               l2 * __expf(m2 - mn) + l3 * __expf(m3 - mn);
    size_t g = (size_t)(rb * BM + tid) * NPART + cb;
    pm[g] = mn;
    pl[g] = ll;
  }

#undef STGA
#undef STGB
#undef DSR
#undef RD4
#undef MFMA_PH
#undef TOPN
#undef BOT
#undef BOTVM
#undef KT
}

// ---------------- loss stage 1: 128 blocks x 64 rows, partial sums ----------------
__global__ void loss_stage1_kernel(const float* __restrict__ pm, const float* __restrict__ pl,
                                   const float* __restrict__ dg, float* __restrict__ partial) {
  const int tid = threadIdx.x;        // 64 threads, one row each
  const int r   = blockIdx.x * L1R + tid;

  const float4* pmr = reinterpret_cast<const float4*>(pm + (size_t)r * NPART);
  const float4* plr = reinterpret_cast<const float4*>(pl + (size_t)r * NPART);

  float m = -1e30f, l = 0.f;
#pragma unroll
  for (int q = 0; q < NPART / 4; ++q) {
    float4 mv = pmr[q];
    float4 lv = plr[q];
#pragma unroll
    for (int k = 0; k < 4; ++k) {
      float m2 = (&mv.x)[k], l2 = (&lv.x)[k];
      float mn = fmaxf(m, m2);
      l = l * __expf(m - mn) + l2 * __expf(m2 - mn);
      m = mn;
    }
  }
  float local = m + __logf(l) - dg[r];

#pragma unroll
  for (int off = 32; off; off >>= 1) local += __shfl_xor(local, off, 64);
  if (tid == 0) partial[blockIdx.x] = local;
}

// ---------------- loss stage 2: reduce 128 partials -> loss ----------------
__global__ void loss_stage2_kernel(const float* __restrict__ partial, float* __restrict__ out) {
  const int tid = threadIdx.x;        // 128 threads
  float v = partial[tid];
#pragma unroll
  for (int off = 32; off; off >>= 1) v += __shfl_xor(v, off, 64);
  __shared__ float red[2];
  if ((tid & 63) == 0) red[tid >> 6] = v;
  __syncthreads();
  if (tid == 0) out[0] = (red[0] + red[1]) / (float)BS;
}

extern "C" void kernel_launch(void* const* d_in, const int* in_sizes, int n_in,
                              void* d_out, int out_size, void* d_ws, size_t ws_size,
                              hipStream_t stream) {
  const float* nl = (const float*)d_in[0];
  const float* cd = (const float*)d_in[1];
  float* out = (float*)d_out;

  const size_t NEL = (size_t)BS * DIM;

  unsigned short* nlb = (unsigned short*)d_ws;       // NEL bf16
  unsigned short* cdb = nlb + NEL;                   // NEL bf16
  float* pm = (float*)(cdb + NEL);                   // BS*NPART
  float* pl = pm + (size_t)BS * NPART;               // BS*NPART
  float* dg = pl + (size_t)BS * NPART;               // BS
  float* partial = dg + BS;                          // L1B

  // out = [loss, code_vec copy, nl_vec copy]
  prep_kernel<<<BS / 4, 256, 0, stream>>>(nl, cd, out + 1, out + 1 + NEL, nlb, cdb, dg);
  gemm_lse_kernel<<<dim3(32, 32), 512, 0, stream>>>(nlb, cdb, pm, pl);
  loss_stage1_kernel<<<L1B, 64, 0, stream>>>(pm, pl, dg, partial);
  loss_stage2_kernel<<<1, 128, 0, stream>>>(partial, out);
}